// Round 11
// baseline (1156.033 us; speedup 1.0000x reference)
//
#include <hip/hip_runtime.h>
#include <math.h>

#define NN 1024
#define HID 64
#define HEADD 128
#define NODE_DIM 14
#define BATCH 32
#define CAP 64
#define ROWS (BATCH * NN)   // 32768
#define RPW 8               // rows per wave in layer kernels

// DIAGNOSTIC ROUND: each kernel's body runs `reps` times inside a loop whose
// address arithmetic depends on (zero & junk_bits) with zero=0 at runtime --
// compiler cannot hoist/CSE the body; outputs are written on the last rep
// only, so results are bit-identical to the R10 kernel. Purpose: push every
// kernel past the 77us harness fill so all five surface in top-5 rocprof
// rows with per-kernel VGPR/Occupancy/VALUBusy/FETCH.

// ---- swizzles (XCD-aware: blk%8 pins a batch's slab to one XCD L2) --------
__device__ __forceinline__ int swz4(int blk, int wv) {
    int x = blk & 7, q = blk >> 3;
    int batch = x + 8 * (q >> 8);
    return batch * NN + ((q & 255) << 2) + wv;
}
__device__ __forceinline__ int swz32(int blk, int wv) {
    int x = blk & 7, q = blk >> 3;          // q in [0,128)
    int batch = x + 8 * (q >> 5);
    return batch * NN + ((q & 31) << 5) + wv * RPW;
}

__device__ __forceinline__ float rl_f(float v, int k) {
    return __int_as_float(__builtin_amdgcn_readlane(__float_as_int(v), k));
}

// ---------------- K1: CSR build (ballot) + g1 = x @ W1 + zero pooled --------
__global__ __launch_bounds__(256) void k_build(const float* __restrict__ adj,
                                               const float* __restrict__ x,
                                               const float* __restrict__ W1,
                                               unsigned short* __restrict__ csr,
                                               int* __restrict__ nnz_g,
                                               float* __restrict__ dinv,
                                               float* __restrict__ g1,
                                               float* __restrict__ pooled,
                                               int reps, int zero,
                                               float* __restrict__ junk_sink) {
    __shared__ float sW1[NODE_DIM * HID];
    for (int i = threadIdx.x; i < NODE_DIM * HID; i += 256) sW1[i] = W1[i];
    if (blockIdx.x < 8) pooled[blockIdx.x * 256 + threadIdx.x] = 0.f;
    int wv = threadIdx.x >> 6, lane = threadIdx.x & 63;
    int row = swz4(blockIdx.x, wv);
    unsigned long long lt = ((unsigned long long)1 << lane) - 1;
    __syncthreads();
    float junk = 0.f;
    for (int rep = 0; rep < reps; ++rep) {
        int z2 = zero & __float_as_int(junk);        // 0 at runtime, opaque
        const float4* rp = reinterpret_cast<const float4*>(adj + (size_t)(row + z2) * NN);
        int base = 0;
#pragma unroll
        for (int j = 0; j < 4; ++j) {
            float4 v = rp[lane + 64 * j];
            float vv[4] = {v.x, v.y, v.z, v.w};
#pragma unroll
            for (int k = 0; k < 4; ++k) {
                unsigned long long mk = __ballot(vv[k] != 0.0f);
                if (mk) {
                    if (vv[k] != 0.0f) {
                        int pos = base + __popcll(mk & lt);
                        if (pos < CAP)
                            csr[row * CAP + pos] = (unsigned short)((lane + 64 * j) * 4 + k);
                    }
                    base += __popcll(mk);
                }
            }
        }
        if (lane == 0 && rep == reps - 1) {
            nnz_g[row] = base < CAP ? base : CAP;
            dinv[row] = 1.0f / sqrtf((float)(base < 1 ? 1 : base));
        }
        float acc = 0.f;
        const float* xr = x + (size_t)(row + z2) * NODE_DIM;
#pragma unroll
        for (int d = 0; d < NODE_DIM; ++d) acc += xr[d] * sW1[d * HID + lane];
        if (rep == reps - 1) g1[(size_t)row * HID + lane] = acc;
        junk = junk * 1.0000001f + acc + (float)base;
    }
    junk_sink[threadIdx.x] = junk;
}

// 8-row interleaved SpMM: per k-step, 8 independent gathers in flight.
__device__ __forceinline__ void spmm8(const float* __restrict__ g_in,
                                      int bbase, const int n[RPW],
                                      const int idx[RPW], const float dv[RPW],
                                      int lane, float acc[RPW]) {
    int nmax = 0;
#pragma unroll
    for (int r = 0; r < RPW; ++r) { acc[r] = 0.f; nmax = n[r] > nmax ? n[r] : nmax; }
    for (int k = 0; k < nmax; ++k) {
        float w[RPW], v[RPW];
#pragma unroll
        for (int r = 0; r < RPW; ++r) {
            int j = __builtin_amdgcn_readlane(idx[r], k);
            w[r] = rl_f(dv[r], k);
            v[r] = g_in[(bbase + j) * HID + lane];
        }
#pragma unroll
        for (int r = 0; r < RPW; ++r) acc[r] += w[r] * v[r];
    }
}

// ---------------- K2/K3: g_out = relu(D A D g_in + bias) @ W ----------------
__global__ __launch_bounds__(256, 4) void k_layer(const float* __restrict__ g_in,
                                                  const unsigned short* __restrict__ csr,
                                                  const int* __restrict__ nnz_g,
                                                  const float* __restrict__ dinv,
                                                  const float* __restrict__ bias,
                                                  const float* __restrict__ W,
                                                  float* __restrict__ g_out,
                                                  int reps, int zero,
                                                  float* __restrict__ junk_sink) {
    __shared__ float sW[HID * HID];            // 16 KB
    for (int i = threadIdx.x; i < HID * HID; i += 256) sW[i] = W[i];
    int wv = threadIdx.x >> 6, lane = threadIdx.x & 63;
    int row0 = swz32(blockIdx.x, wv);
    float bb = bias[lane];
    __syncthreads();                           // sW ready
    float junk = 0.f;
    for (int rep = 0; rep < reps; ++rep) {
        int z2 = zero & __float_as_int(junk);  // 0 at runtime, opaque
        int bbase = (row0 & ~(NN - 1)) + z2;
        int n[RPW], idx[RPW];
        float dv[RPW];
#pragma unroll
        for (int r = 0; r < RPW; ++r) {
            int row = row0 + r;
            n[r] = __builtin_amdgcn_readfirstlane(nnz_g[row + z2]);
            idx[r] = (lane < n[r]) ? (int)csr[(row + z2) * CAP + lane] : 0;
            dv[r] = (lane < n[r]) ? dinv[bbase + idx[r]] : 0.f;
        }
        float acc[RPW];
        spmm8(g_in, bbase, n, idx, dv, lane, acc);
        float h[RPW];
#pragma unroll
        for (int r = 0; r < RPW; ++r)
            h[r] = fmaxf(dinv[row0 + r + z2] * acc[r] + bb, 0.f);
        float o[RPW];
#pragma unroll
        for (int r = 0; r < RPW; ++r) o[r] = 0.f;
        for (int d = 0; d < HID; ++d) {
            float w = sW[d * HID + lane];
#pragma unroll
            for (int r = 0; r < RPW; ++r) o[r] += rl_f(h[r], d) * w;
        }
        if (rep == reps - 1) {
#pragma unroll
            for (int r = 0; r < RPW; ++r)
                g_out[(size_t)(row0 + r) * HID + lane] = o[r];
        }
        junk = junk * 1.0000001f + o[0] + o[RPW - 1];
    }
    junk_sink[threadIdx.x] = junk;
}

// ---------------- K4: h3 = relu(DAD g3 + b3); pool --------------------------
__global__ __launch_bounds__(256, 4) void k_layer3(const float* __restrict__ g_in,
                                                   const unsigned short* __restrict__ csr,
                                                   const int* __restrict__ nnz_g,
                                                   const float* __restrict__ dinv,
                                                   const float* __restrict__ bias,
                                                   float* __restrict__ pooled,
                                                   int reps, int zero,
                                                   float* __restrict__ junk_sink) {
    __shared__ float sred[4][HID];
    int wv = threadIdx.x >> 6, lane = threadIdx.x & 63;
    int row0 = swz32(blockIdx.x, wv);
    float bb = bias[lane];
    float junk = 0.f;
    for (int rep = 0; rep < reps; ++rep) {
        int z2 = zero & __float_as_int(junk);
        int bbase = (row0 & ~(NN - 1)) + z2;
        int n[RPW], idx[RPW];
        float dv[RPW];
#pragma unroll
        for (int r = 0; r < RPW; ++r) {
            int row = row0 + r;
            n[r] = __builtin_amdgcn_readfirstlane(nnz_g[row + z2]);
            idx[r] = (lane < n[r]) ? (int)csr[(row + z2) * CAP + lane] : 0;
            dv[r] = (lane < n[r]) ? dinv[bbase + idx[r]] : 0.f;
        }
        float acc[RPW];
        spmm8(g_in, bbase, n, idx, dv, lane, acc);
        float s = 0.f;
#pragma unroll
        for (int r = 0; r < RPW; ++r)
            s += fmaxf(dinv[row0 + r + z2] * acc[r] + bb, 0.f);
        if (rep == reps - 1) {                 // uniform condition
            sred[wv][lane] = s;
            __syncthreads();
            if (wv == 0) {
                float tot = sred[0][lane] + sred[1][lane] + sred[2][lane] + sred[3][lane];
                atomicAdd(&pooled[((row0 & ~(NN - 1)) >> 10) * HID + lane], tot);
            }
        }
        junk = junk * 1.0000001f + s;
    }
    junk_sink[threadIdx.x] = junk;
}

// ---------------- K5: head ---------------------------------------------------
__global__ __launch_bounds__(128) void k_head(const float* __restrict__ pooled_sum,
                                              const float* __restrict__ Wf1,
                                              const float* __restrict__ bf1,
                                              const float* __restrict__ Wf2,
                                              const float* __restrict__ bf2,
                                              float* __restrict__ out,
                                              int reps, int zero,
                                              float* __restrict__ junk_sink) {
    int b = blockIdx.x, t = threadIdx.x;
    __shared__ float p[HID];
    __shared__ float hid[HEADD];
    float junk = 0.f;
    for (int rep = 0; rep < reps; ++rep) {
        int z2 = zero & __float_as_int(junk);
        if (t < HID) p[t] = pooled_sum[(b + z2) * HID + t] * (1.0f / NN);
        __syncthreads();
        float acc = bf1[t];
        for (int d = 0; d < HID; ++d) acc += p[d] * Wf1[(d + z2) * HEADD + t];
        hid[t] = fmaxf(acc, 0.f);
        __syncthreads();
        if (t < 64) {
            float v = hid[t] * Wf2[t + z2] + hid[t + 64] * Wf2[t + 64];
#pragma unroll
            for (int off = 32; off > 0; off >>= 1) v += __shfl_down(v, off, 64);
            if (t == 0 && rep == reps - 1) out[b] = v + bf2[0];
            junk = junk * 1.0000001f + v;
        }
        __syncthreads();
    }
    junk_sink[t] = junk;
}

extern "C" void kernel_launch(void* const* d_in, const int* in_sizes, int n_in,
                              void* d_out, int out_size, void* d_ws, size_t ws_size,
                              hipStream_t stream) {
    const float* x   = (const float*)d_in[0];
    const float* adj = (const float*)d_in[1];
    const float* W1  = (const float*)d_in[2];
    const float* b1  = (const float*)d_in[3];
    const float* W2  = (const float*)d_in[4];
    const float* b2  = (const float*)d_in[5];
    const float* W3  = (const float*)d_in[6];
    const float* b3  = (const float*)d_in[7];
    const float* Wf1 = (const float*)d_in[8];
    const float* bf1 = (const float*)d_in[9];
    const float* Wf2 = (const float*)d_in[10];
    const float* bf2 = (const float*)d_in[11];
    float* out = (float*)d_out;

    // ws carve: csr(ushort) 4MB | nnz | dinv | pooled | junk | g1,g2,g3 8MB
    char* ws = (char*)d_ws;
    size_t off = 0;
    unsigned short* csr = (unsigned short*)(ws + off); off += (size_t)ROWS * CAP * 2;
    int*   nnz_g  = (int*)(ws + off);   off += (size_t)ROWS * 4;
    float* dinv   = (float*)(ws + off); off += (size_t)ROWS * 4;
    float* pooled = (float*)(ws + off); off += 4096 * 4;
    float* junks  = (float*)(ws + off); off += 1024 * 4;
    float* g1     = (float*)(ws + off); off += (size_t)ROWS * HID * 4;
    float* g2     = (float*)(ws + off); off += (size_t)ROWS * HID * 4;
    float* g3     = (float*)(ws + off);

    const int ZERO = 0;   // runtime-opaque zero for the diagnostic loops

    k_build <<<ROWS / 4, 256, 0, stream>>>(adj, x, W1, csr, nnz_g, dinv, g1,
                                           pooled, 8, ZERO, junks);
    k_layer <<<ROWS / 32, 256, 0, stream>>>(g1, csr, nnz_g, dinv, b1, W2, g2,
                                            10, ZERO, junks);
    k_layer <<<ROWS / 32, 256, 0, stream>>>(g2, csr, nnz_g, dinv, b2, W3, g3,
                                            10, ZERO, junks);
    k_layer3<<<ROWS / 32, 256, 0, stream>>>(g3, csr, nnz_g, dinv, b3, pooled,
                                            10, ZERO, junks);
    k_head  <<<BATCH, 128, 0, stream>>>(pooled, Wf1, bf1, Wf2, bf2, out,
                                        48, ZERO, junks);
}

// Round 12
// 705.445 us; speedup vs baseline: 1.6387x; 1.6387x over previous
//
#include <hip/hip_runtime.h>
#include <math.h>

#define NN 1024
#define HID 64
#define HEADD 128
#define NODE_DIM 14
#define BATCH 32
#define CAP 64
#define ROWS (BATCH * NN)   // 32768
#define RPW 8               // rows per wave in layer kernels

// ---- swizzles (XCD-aware: blk%8 pins a batch's slab to one XCD L2) --------
__device__ __forceinline__ int swz4(int blk, int wv) {
    int x = blk & 7, q = blk >> 3;
    int batch = x + 8 * (q >> 8);
    return batch * NN + ((q & 255) << 2) + wv;
}
__device__ __forceinline__ int swz32(int blk, int wv) {
    int x = blk & 7, q = blk >> 3;          // q in [0,128)
    int batch = x + 8 * (q >> 5);
    return batch * NN + ((q & 31) << 5) + wv * RPW;
}

__device__ __forceinline__ float rl_f(float v, int k) {
    return __int_as_float(__builtin_amdgcn_readlane(__float_as_int(v), k));
}

// ---------------- K1: CSR build (ballot) + g1 = x @ W1 + zero pooled --------
__global__ __launch_bounds__(256) void k_build(const float* __restrict__ adj,
                                               const float* __restrict__ x,
                                               const float* __restrict__ W1,
                                               unsigned short* __restrict__ csr,
                                               int* __restrict__ nnz_g,
                                               float* __restrict__ dinv,
                                               float* __restrict__ g1,
                                               float* __restrict__ pooled) {
    __shared__ float sW1[NODE_DIM * HID];
    for (int i = threadIdx.x; i < NODE_DIM * HID; i += 256) sW1[i] = W1[i];
    if (blockIdx.x < 8) pooled[blockIdx.x * 256 + threadIdx.x] = 0.f;
    int wv = threadIdx.x >> 6, lane = threadIdx.x & 63;
    int row = swz4(blockIdx.x, wv);
    const float4* rp = reinterpret_cast<const float4*>(adj + (size_t)row * NN);
    unsigned long long lt = ((unsigned long long)1 << lane) - 1;
    int base = 0;
#pragma unroll
    for (int j = 0; j < 4; ++j) {
        float4 v = rp[lane + 64 * j];
        float vv[4] = {v.x, v.y, v.z, v.w};
#pragma unroll
        for (int k = 0; k < 4; ++k) {
            unsigned long long mk = __ballot(vv[k] != 0.0f);
            if (mk) {
                if (vv[k] != 0.0f) {
                    int pos = base + __popcll(mk & lt);
                    if (pos < CAP)
                        csr[row * CAP + pos] = (unsigned short)((lane + 64 * j) * 4 + k);
                }
                base += __popcll(mk);
            }
        }
    }
    if (lane == 0) {
        nnz_g[row] = base < CAP ? base : CAP;
        dinv[row] = 1.0f / sqrtf((float)(base < 1 ? 1 : base));
    }
    __syncthreads();
    float acc = 0.f;
    const float* xr = x + (size_t)row * NODE_DIM;
#pragma unroll
    for (int d = 0; d < NODE_DIM; ++d) acc += xr[d] * sW1[d * HID + lane];
    g1[(size_t)row * HID + lane] = acc;
}

// 8-row interleaved SpMM: per k-step, 8 independent gathers in flight.
__device__ __forceinline__ void spmm8(const float* __restrict__ g_in,
                                      int bbase, const int n[RPW],
                                      const int idx[RPW], const float dv[RPW],
                                      int lane, float acc[RPW]) {
    int nmax = 0;
#pragma unroll
    for (int r = 0; r < RPW; ++r) { acc[r] = 0.f; nmax = n[r] > nmax ? n[r] : nmax; }
    for (int k = 0; k < nmax; ++k) {
        float w[RPW], v[RPW];
#pragma unroll
        for (int r = 0; r < RPW; ++r) {
            int j = __builtin_amdgcn_readlane(idx[r], k);
            w[r] = rl_f(dv[r], k);
            v[r] = g_in[(bbase + j) * HID + lane];
        }
#pragma unroll
        for (int r = 0; r < RPW; ++r) acc[r] += w[r] * v[r];
    }
}

// Shared body for one 8-row chunk: returns o[] for rows row0..row0+7.
__device__ __forceinline__ void layer_chunk(const float* __restrict__ g_in,
                                            const unsigned short* __restrict__ csr,
                                            const int* __restrict__ nnz_g,
                                            const float* __restrict__ dinv,
                                            float bb, const float wreg[HID],
                                            int row0, int bbase, int lane,
                                            float o[RPW]) {
    int n[RPW], idx[RPW];
    float dv[RPW];
#pragma unroll
    for (int r = 0; r < RPW; ++r) {
        int row = row0 + r;
        n[r] = __builtin_amdgcn_readfirstlane(nnz_g[row]);
        idx[r] = (lane < n[r]) ? (int)csr[row * CAP + lane] : 0;
        dv[r] = (lane < n[r]) ? dinv[bbase + idx[r]] : 0.f;
    }
    float acc[RPW];
    spmm8(g_in, bbase, n, idx, dv, lane, acc);
    float h[RPW];
#pragma unroll
    for (int r = 0; r < RPW; ++r)
        h[r] = fmaxf(dinv[row0 + r] * acc[r] + bb, 0.f);
#pragma unroll
    for (int r = 0; r < RPW; ++r) o[r] = 0.f;
#pragma unroll
    for (int d = 0; d < HID; ++d) {
        float w = wreg[d];
#pragma unroll
        for (int r = 0; r < RPW; ++r) o[r] += rl_f(h[r], d) * w;
    }
}

// ---------------- K2-AMPLIFIED (diagnostic): first layer, reps x ------------
// Earlier reps process a rep-shifted row window in the SAME batch (addresses
// depend only on rep -> loads pipeline across reps, no CSE possible, no
// serialization). Only the last rep (shift=0, canonical rows) writes g_out.
__global__ __launch_bounds__(256, 4) void k_layer_amp(const float* __restrict__ g_in,
                                                      const unsigned short* __restrict__ csr,
                                                      const int* __restrict__ nnz_g,
                                                      const float* __restrict__ dinv,
                                                      const float* __restrict__ bias,
                                                      const float* __restrict__ W,
                                                      float* __restrict__ g_out,
                                                      int reps,
                                                      float* __restrict__ junk_sink) {
    int wv = threadIdx.x >> 6, lane = threadIdx.x & 63;
    float wreg[HID];
#pragma unroll
    for (int d = 0; d < HID; ++d) wreg[d] = W[d * HID + lane];
    int row0 = swz32(blockIdx.x, wv);
    int bbase = row0 & ~(NN - 1);
    int local0 = row0 - bbase;
    float bb = bias[lane];
    float junk = 0.f;
#pragma unroll 1
    for (int rep = 0; rep < reps; ++rep) {
        int shift = (rep == reps - 1) ? 0 : ((rep & 31) + 1) * 32;
        int row0p = bbase + ((local0 + shift) & (NN - 1));
        float o[RPW];
        layer_chunk(g_in, csr, nnz_g, dinv, bb, wreg, row0p, bbase, lane, o);
        if (rep == reps - 1) {
#pragma unroll
            for (int r = 0; r < RPW; ++r)
                g_out[(size_t)(row0p + r) * HID + lane] = o[r];
        }
        junk += o[0] + o[RPW - 1];
    }
    junk_sink[threadIdx.x] = junk;
}

// ---------------- K3: normal layer (R9 form) --------------------------------
__global__ __launch_bounds__(256, 4) void k_layer(const float* __restrict__ g_in,
                                                  const unsigned short* __restrict__ csr,
                                                  const int* __restrict__ nnz_g,
                                                  const float* __restrict__ dinv,
                                                  const float* __restrict__ bias,
                                                  const float* __restrict__ W,
                                                  float* __restrict__ g_out) {
    int wv = threadIdx.x >> 6, lane = threadIdx.x & 63;
    float wreg[HID];
#pragma unroll
    for (int d = 0; d < HID; ++d) wreg[d] = W[d * HID + lane];
    int row0 = swz32(blockIdx.x, wv);
    int bbase = row0 & ~(NN - 1);
    float bb = bias[lane];
    float o[RPW];
    layer_chunk(g_in, csr, nnz_g, dinv, bb, wreg, row0, bbase, lane, o);
#pragma unroll
    for (int r = 0; r < RPW; ++r)
        g_out[(size_t)(row0 + r) * HID + lane] = o[r];
}

// ---------------- K4: h3 = relu(DAD g3 + b3); pool --------------------------
__global__ __launch_bounds__(256, 4) void k_layer3(const float* __restrict__ g_in,
                                                   const unsigned short* __restrict__ csr,
                                                   const int* __restrict__ nnz_g,
                                                   const float* __restrict__ dinv,
                                                   const float* __restrict__ bias,
                                                   float* __restrict__ pooled) {
    __shared__ float sred[4][HID];
    int wv = threadIdx.x >> 6, lane = threadIdx.x & 63;
    int row0 = swz32(blockIdx.x, wv);
    int bbase = row0 & ~(NN - 1);
    float bb = bias[lane];
    int n[RPW], idx[RPW];
    float dv[RPW];
#pragma unroll
    for (int r = 0; r < RPW; ++r) {
        int row = row0 + r;
        n[r] = __builtin_amdgcn_readfirstlane(nnz_g[row]);
        idx[r] = (lane < n[r]) ? (int)csr[row * CAP + lane] : 0;
        dv[r] = (lane < n[r]) ? dinv[bbase + idx[r]] : 0.f;
    }
    float acc[RPW];
    spmm8(g_in, bbase, n, idx, dv, lane, acc);
    float s = 0.f;
#pragma unroll
    for (int r = 0; r < RPW; ++r)
        s += fmaxf(dinv[row0 + r] * acc[r] + bb, 0.f);
    sred[wv][lane] = s;
    __syncthreads();
    if (wv == 0) {
        float tot = sred[0][lane] + sred[1][lane] + sred[2][lane] + sred[3][lane];
        atomicAdd(&pooled[(bbase >> 10) * HID + lane], tot);
    }
}

// ---------------- K5: head ---------------------------------------------------
__global__ __launch_bounds__(128) void k_head(const float* __restrict__ pooled_sum,
                                              const float* __restrict__ Wf1,
                                              const float* __restrict__ bf1,
                                              const float* __restrict__ Wf2,
                                              const float* __restrict__ bf2,
                                              float* __restrict__ out) {
    int b = blockIdx.x, t = threadIdx.x;
    __shared__ float p[HID];
    __shared__ float hid[HEADD];
    if (t < HID) p[t] = pooled_sum[b * HID + t] * (1.0f / NN);
    __syncthreads();
    float acc = bf1[t];
    for (int d = 0; d < HID; ++d) acc += p[d] * Wf1[d * HEADD + t];
    hid[t] = fmaxf(acc, 0.f);
    __syncthreads();
    if (t < 64) {
        float v = hid[t] * Wf2[t] + hid[t + 64] * Wf2[t + 64];
#pragma unroll
        for (int off = 32; off > 0; off >>= 1) v += __shfl_down(v, off, 64);
        if (t == 0) out[b] = v + bf2[0];
    }
}

extern "C" void kernel_launch(void* const* d_in, const int* in_sizes, int n_in,
                              void* d_out, int out_size, void* d_ws, size_t ws_size,
                              hipStream_t stream) {
    const float* x   = (const float*)d_in[0];
    const float* adj = (const float*)d_in[1];
    const float* W1  = (const float*)d_in[2];
    const float* b1  = (const float*)d_in[3];
    const float* W2  = (const float*)d_in[4];
    const float* b2  = (const float*)d_in[5];
    const float* W3  = (const float*)d_in[6];
    const float* b3  = (const float*)d_in[7];
    const float* Wf1 = (const float*)d_in[8];
    const float* bf1 = (const float*)d_in[9];
    const float* Wf2 = (const float*)d_in[10];
    const float* bf2 = (const float*)d_in[11];
    float* out = (float*)d_out;

    // ws carve: csr(ushort) 4MB | nnz | dinv | pooled | junk | g1,g2,g3 8MB
    char* ws = (char*)d_ws;
    size_t off = 0;
    unsigned short* csr = (unsigned short*)(ws + off); off += (size_t)ROWS * CAP * 2;
    int*   nnz_g  = (int*)(ws + off);   off += (size_t)ROWS * 4;
    float* dinv   = (float*)(ws + off); off += (size_t)ROWS * 4;
    float* pooled = (float*)(ws + off); off += 4096 * 4;
    float* junks  = (float*)(ws + off); off += 1024 * 4;
    float* g1     = (float*)(ws + off); off += (size_t)ROWS * HID * 4;
    float* g2     = (float*)(ws + off); off += (size_t)ROWS * HID * 4;
    float* g3     = (float*)(ws + off);

    k_build    <<<ROWS / 4, 256, 0, stream>>>(adj, x, W1, csr, nnz_g, dinv, g1, pooled);
    k_layer_amp<<<ROWS / 32, 256, 0, stream>>>(g1, csr, nnz_g, dinv, b1, W2, g2,
                                               24, junks);   // DIAGNOSTIC x24
    k_layer    <<<ROWS / 32, 256, 0, stream>>>(g2, csr, nnz_g, dinv, b2, W3, g3);
    k_layer3   <<<ROWS / 32, 256, 0, stream>>>(g3, csr, nnz_g, dinv, b3, pooled);
    k_head     <<<BATCH, 128, 0, stream>>>(pooled, Wf1, bf1, Wf2, bf2, out);
}

// Round 13
// 340.397 us; speedup vs baseline: 3.3961x; 2.0724x over previous
//
#include <hip/hip_runtime.h>
#include <math.h>

#define NN 1024
#define HID 64
#define HEADD 128
#define NODE_DIM 14
#define BATCH 32
#define CAP 64
#define ROWS (BATCH * NN)   // 32768
#define RPW 8               // rows per wave in layer kernels

// ---- swizzles (XCD-aware: blk%8 pins a batch's slab to one XCD L2) --------
__device__ __forceinline__ int swz4(int blk, int wv) {
    int x = blk & 7, q = blk >> 3;
    int batch = x + 8 * (q >> 8);
    return batch * NN + ((q & 255) << 2) + wv;
}
__device__ __forceinline__ int swz32(int blk, int wv) {
    int x = blk & 7, q = blk >> 3;          // q in [0,128)
    int batch = x + 8 * (q >> 5);
    return batch * NN + ((q & 31) << 5) + wv * RPW;
}

// ---------------- K1: CSR build (ballot) + g1 = x @ W1 + zero pooled --------
__global__ __launch_bounds__(256) void k_build(const float* __restrict__ adj,
                                               const float* __restrict__ x,
                                               const float* __restrict__ W1,
                                               int* __restrict__ csr,
                                               int* __restrict__ nnz_g,
                                               float* __restrict__ dinv,
                                               float* __restrict__ g1,
                                               float* __restrict__ pooled) {
    __shared__ float sW1[NODE_DIM * HID];
    for (int i = threadIdx.x; i < NODE_DIM * HID; i += 256) sW1[i] = W1[i];
    if (blockIdx.x < 8) pooled[blockIdx.x * 256 + threadIdx.x] = 0.f;
    int wv = threadIdx.x >> 6, lane = threadIdx.x & 63;
    int row = swz4(blockIdx.x, wv);
    const float4* rp = reinterpret_cast<const float4*>(adj + (size_t)row * NN);
    unsigned long long lt = ((unsigned long long)1 << lane) - 1;
    int base = 0;
#pragma unroll
    for (int j = 0; j < 4; ++j) {
        float4 v = rp[lane + 64 * j];
        float vv[4] = {v.x, v.y, v.z, v.w};
#pragma unroll
        for (int k = 0; k < 4; ++k) {
            unsigned long long mk = __ballot(vv[k] != 0.0f);
            if (mk) {
                if (vv[k] != 0.0f) {
                    int pos = base + __popcll(mk & lt);
                    if (pos < CAP) csr[row * CAP + pos] = (lane + 64 * j) * 4 + k;
                }
                base += __popcll(mk);
            }
        }
    }
    if (lane == 0) {
        nnz_g[row] = base < CAP ? base : CAP;
        dinv[row] = 1.0f / sqrtf((float)(base < 1 ? 1 : base));
    }
    __syncthreads();
    float acc = 0.f;
    const float* xr = x + (size_t)row * NODE_DIM;
#pragma unroll
    for (int d = 0; d < NODE_DIM; ++d) acc += xr[d] * sW1[d * HID + lane];
    g1[(size_t)row * HID + lane] = acc;
}

// ---------------- kB: h = relu(D A D g_in + bias) ---------------------------
// All indices/weights wave-uniform -> scalar loads (SMEM pipe), VALU does
// only 8 fmacs per k-step. Gathers coalesced 256B, L2-resident (R12: 7.5MB).
__global__ __launch_bounds__(256, 4) void k_gather(const float* __restrict__ g_in,
                                                   const int* __restrict__ csr,
                                                   const int* __restrict__ nnz_g,
                                                   const float* __restrict__ dinv,
                                                   const float* __restrict__ bias,
                                                   float* __restrict__ h_out) {
    int wv = threadIdx.x >> 6, lane = threadIdx.x & 63;
    int row0 = __builtin_amdgcn_readfirstlane(swz32(blockIdx.x, wv));
    int bbase = row0 & ~(NN - 1);
    float bb = bias[lane];
    int n[RPW];
    int nmax = 0;
#pragma unroll
    for (int r = 0; r < RPW; ++r) {
        n[r] = __builtin_amdgcn_readfirstlane(nnz_g[row0 + r]);
        nmax = n[r] > nmax ? n[r] : nmax;
    }
    float acc[RPW];
#pragma unroll
    for (int r = 0; r < RPW; ++r) acc[r] = 0.f;
    for (int k = 0; k < nmax; ++k) {
        float w[RPW];
        int jj[RPW];
#pragma unroll
        for (int r = 0; r < RPW; ++r) {
            int jraw = csr[(row0 + r) * CAP + k];        // uniform -> s_load
            int j = (k < n[r]) ? jraw : 0;               // scalar select (safe pad)
            float dvj = dinv[bbase + j];                 // uniform -> s_load
            w[r] = (k < n[r]) ? dvj : 0.f;               // exact +0.0 padding
            jj[r] = j;
        }
        float v[RPW];
#pragma unroll
        for (int r = 0; r < RPW; ++r)
            v[r] = g_in[(size_t)(bbase + jj[r]) * HID + lane];  // saddr + lane
#pragma unroll
        for (int r = 0; r < RPW; ++r) acc[r] += w[r] * v[r];
    }
#pragma unroll
    for (int r = 0; r < RPW; ++r) {
        float di = dinv[row0 + r];                       // uniform
        h_out[(size_t)(row0 + r) * HID + lane] = fmaxf(di * acc[r] + bb, 0.f);
    }
}

// ---------------- kB3: last gather + pool (no @W after) ---------------------
__global__ __launch_bounds__(256, 4) void k_gather3(const float* __restrict__ g_in,
                                                    const int* __restrict__ csr,
                                                    const int* __restrict__ nnz_g,
                                                    const float* __restrict__ dinv,
                                                    const float* __restrict__ bias,
                                                    float* __restrict__ pooled) {
    __shared__ float sred[4][HID];
    int wv = threadIdx.x >> 6, lane = threadIdx.x & 63;
    int row0 = __builtin_amdgcn_readfirstlane(swz32(blockIdx.x, wv));
    int bbase = row0 & ~(NN - 1);
    float bb = bias[lane];
    int n[RPW];
    int nmax = 0;
#pragma unroll
    for (int r = 0; r < RPW; ++r) {
        n[r] = __builtin_amdgcn_readfirstlane(nnz_g[row0 + r]);
        nmax = n[r] > nmax ? n[r] : nmax;
    }
    float acc[RPW];
#pragma unroll
    for (int r = 0; r < RPW; ++r) acc[r] = 0.f;
    for (int k = 0; k < nmax; ++k) {
        float w[RPW];
        int jj[RPW];
#pragma unroll
        for (int r = 0; r < RPW; ++r) {
            int jraw = csr[(row0 + r) * CAP + k];
            int j = (k < n[r]) ? jraw : 0;
            float dvj = dinv[bbase + j];
            w[r] = (k < n[r]) ? dvj : 0.f;
            jj[r] = j;
        }
        float v[RPW];
#pragma unroll
        for (int r = 0; r < RPW; ++r)
            v[r] = g_in[(size_t)(bbase + jj[r]) * HID + lane];
#pragma unroll
        for (int r = 0; r < RPW; ++r) acc[r] += w[r] * v[r];
    }
    float s = 0.f;
#pragma unroll
    for (int r = 0; r < RPW; ++r) {
        float di = dinv[row0 + r];
        s += fmaxf(di * acc[r] + bb, 0.f);
    }
    sred[wv][lane] = s;
    __syncthreads();
    if (wv == 0) {
        float tot = sred[0][lane] + sred[1][lane] + sred[2][lane] + sred[3][lane];
        atomicAdd(&pooled[(bbase >> 10) * HID + lane], tot);
    }
}

// ---------------- kA: g = h @ W ---------------------------------------------
// h rows read via wave-uniform loads (SGPR h, SMEM pipe); W in 64 VGPRs.
// Epilogue is pure v_fmac o, s_h, v_w -> 1 VALU instr per 64 MACs.
// 4 partial sums per row for fmac-chain ILP (reassociation within fp32 noise).
__global__ __launch_bounds__(256, 4) void k_gemm(const float* __restrict__ h_in,
                                                 const float* __restrict__ W,
                                                 float* __restrict__ g_out) {
    int wv = threadIdx.x >> 6, lane = threadIdx.x & 63;
    float wreg[HID];
#pragma unroll
    for (int d = 0; d < HID; ++d) wreg[d] = W[d * HID + lane];
    int row0 = __builtin_amdgcn_readfirstlane(swz32(blockIdx.x, wv));
#pragma unroll
    for (int r = 0; r < RPW; ++r) {
        const float* hrow = h_in + (size_t)(row0 + r) * HID;   // uniform base
        float o0 = 0.f, o1 = 0.f, o2 = 0.f, o3 = 0.f;
#pragma unroll
        for (int d = 0; d < HID; d += 4) {
            o0 += hrow[d]     * wreg[d];
            o1 += hrow[d + 1] * wreg[d + 1];
            o2 += hrow[d + 2] * wreg[d + 2];
            o3 += hrow[d + 3] * wreg[d + 3];
        }
        g_out[(size_t)(row0 + r) * HID + lane] = (o0 + o1) + (o2 + o3);
    }
}

// ---------------- K5: head ---------------------------------------------------
__global__ __launch_bounds__(128) void k_head(const float* __restrict__ pooled_sum,
                                              const float* __restrict__ Wf1,
                                              const float* __restrict__ bf1,
                                              const float* __restrict__ Wf2,
                                              const float* __restrict__ bf2,
                                              float* __restrict__ out) {
    int b = blockIdx.x, t = threadIdx.x;
    __shared__ float p[HID];
    __shared__ float hid[HEADD];
    if (t < HID) p[t] = pooled_sum[b * HID + t] * (1.0f / NN);
    __syncthreads();
    float acc = bf1[t];
    for (int d = 0; d < HID; ++d) acc += p[d] * Wf1[d * HEADD + t];
    hid[t] = fmaxf(acc, 0.f);
    __syncthreads();
    if (t < 64) {
        float v = hid[t] * Wf2[t] + hid[t + 64] * Wf2[t + 64];
#pragma unroll
        for (int off = 32; off > 0; off >>= 1) v += __shfl_down(v, off, 64);
        if (t == 0) out[b] = v + bf2[0];
    }
}

extern "C" void kernel_launch(void* const* d_in, const int* in_sizes, int n_in,
                              void* d_out, int out_size, void* d_ws, size_t ws_size,
                              hipStream_t stream) {
    const float* x   = (const float*)d_in[0];
    const float* adj = (const float*)d_in[1];
    const float* W1  = (const float*)d_in[2];
    const float* b1  = (const float*)d_in[3];
    const float* W2  = (const float*)d_in[4];
    const float* b2  = (const float*)d_in[5];
    const float* W3  = (const float*)d_in[6];
    const float* b3  = (const float*)d_in[7];
    const float* Wf1 = (const float*)d_in[8];
    const float* bf1 = (const float*)d_in[9];
    const float* Wf2 = (const float*)d_in[10];
    const float* bf2 = (const float*)d_in[11];
    float* out = (float*)d_out;

    // ws carve: csr(int) 8MB | nnz | dinv | pooled | g 8MB | h 8MB
    char* ws = (char*)d_ws;
    size_t off = 0;
    int*   csr    = (int*)(ws + off);   off += (size_t)ROWS * CAP * 4;
    int*   nnz_g  = (int*)(ws + off);   off += (size_t)ROWS * 4;
    float* dinv   = (float*)(ws + off); off += (size_t)ROWS * 4;
    float* pooled = (float*)(ws + off); off += 4096 * 4;
    float* gbuf   = (float*)(ws + off); off += (size_t)ROWS * HID * 4;
    float* hbuf   = (float*)(ws + off);

    k_build  <<<ROWS / 4, 256, 0, stream>>>(adj, x, W1, csr, nnz_g, dinv, gbuf, pooled);
    k_gather <<<ROWS / 32, 256, 0, stream>>>(gbuf, csr, nnz_g, dinv, b1, hbuf);  // h1
    k_gemm   <<<ROWS / 32, 256, 0, stream>>>(hbuf, W2, gbuf);                    // g2
    k_gather <<<ROWS / 32, 256, 0, stream>>>(gbuf, csr, nnz_g, dinv, b2, hbuf);  // h2
    k_gemm   <<<ROWS / 32, 256, 0, stream>>>(hbuf, W3, gbuf);                    // g3
    k_gather3<<<ROWS / 32, 256, 0, stream>>>(gbuf, csr, nnz_g, dinv, b3, pooled);
    k_head   <<<BATCH, 128, 0, stream>>>(pooled, Wf1, bf1, Wf2, bf2, out);
}

// Round 14
// 314.802 us; speedup vs baseline: 3.6723x; 1.0813x over previous
//
#include <hip/hip_runtime.h>
#include <math.h>

#define NN 1024
#define HID 64
#define HEADD 128
#define NODE_DIM 14
#define BATCH 32
#define CAP 64
#define ROWS (BATCH * NN)   // 32768
#define RPW 8               // rows per wave in layer kernels
#define LAYER_BLOCKS (ROWS / 32)   // 1024

// ---- swizzles (XCD-aware: blk%8 pins a batch's slab to one XCD L2) --------
__device__ __forceinline__ int swz4(int blk, int wv) {
    int x = blk & 7, q = blk >> 3;
    int batch = x + 8 * (q >> 8);
    return batch * NN + ((q & 255) << 2) + wv;
}
__device__ __forceinline__ int swz32(int blk, int wv) {
    int x = blk & 7, q = blk >> 3;          // q in [0,128)
    int batch = x + 8 * (q >> 5);
    return batch * NN + ((q & 31) << 5) + wv * RPW;
}

__device__ __forceinline__ float rl_f(float v, int k) {
    return __int_as_float(__builtin_amdgcn_readlane(__float_as_int(v), k));
}

// ---------------- K1: CSR build (ballot) + g1 = x @ W1 + zero pooled/ticket -
__global__ __launch_bounds__(256) void k_build(const float* __restrict__ adj,
                                               const float* __restrict__ x,
                                               const float* __restrict__ W1,
                                               int* __restrict__ csr,
                                               int* __restrict__ nnz_g,
                                               float* __restrict__ dinv,
                                               float* __restrict__ g1,
                                               float* __restrict__ pooled,
                                               int* __restrict__ ticket) {
    __shared__ float sW1[NODE_DIM * HID];
    for (int i = threadIdx.x; i < NODE_DIM * HID; i += 256) sW1[i] = W1[i];
    if (blockIdx.x < 8) pooled[blockIdx.x * 256 + threadIdx.x] = 0.f;
    if (blockIdx.x == 8 && threadIdx.x == 0) ticket[0] = 0;
    int wv = threadIdx.x >> 6, lane = threadIdx.x & 63;
    int row = swz4(blockIdx.x, wv);
    const float4* rp = reinterpret_cast<const float4*>(adj + (size_t)row * NN);
    unsigned long long lt = ((unsigned long long)1 << lane) - 1;
    int base = 0;
#pragma unroll
    for (int j = 0; j < 4; ++j) {
        float4 v = rp[lane + 64 * j];
        float vv[4] = {v.x, v.y, v.z, v.w};
#pragma unroll
        for (int k = 0; k < 4; ++k) {
            unsigned long long mk = __ballot(vv[k] != 0.0f);
            if (mk) {
                if (vv[k] != 0.0f) {
                    int pos = base + __popcll(mk & lt);
                    if (pos < CAP) csr[row * CAP + pos] = (lane + 64 * j) * 4 + k;
                }
                base += __popcll(mk);
            }
        }
    }
    if (lane == 0) {
        nnz_g[row] = base < CAP ? base : CAP;
        dinv[row] = 1.0f / sqrtf((float)(base < 1 ? 1 : base));
    }
    __syncthreads();
    float acc = 0.f;
    const float* xr = x + (size_t)row * NODE_DIM;
#pragma unroll
    for (int d = 0; d < NODE_DIM; ++d) acc += xr[d] * sW1[d * HID + lane];
    g1[(size_t)row * HID + lane] = acc;
}

// 8-row interleaved SpMM (R9 form, proven): per k-step 8 independent gathers.
__device__ __forceinline__ void spmm8(const float* __restrict__ g_in,
                                      int bbase, const int n[RPW],
                                      const int idx[RPW], const float dv[RPW],
                                      int lane, float acc[RPW]) {
    int nmax = 0;
#pragma unroll
    for (int r = 0; r < RPW; ++r) { acc[r] = 0.f; nmax = n[r] > nmax ? n[r] : nmax; }
    for (int k = 0; k < nmax; ++k) {
        float w[RPW], v[RPW];
#pragma unroll
        for (int r = 0; r < RPW; ++r) {
            int j = __builtin_amdgcn_readlane(idx[r], k);
            w[r] = rl_f(dv[r], k);
            v[r] = g_in[(bbase + j) * HID + lane];
        }
#pragma unroll
        for (int r = 0; r < RPW; ++r) acc[r] += w[r] * v[r];
    }
}

// Gather front-end shared by all layers.
__device__ __forceinline__ void gather_rows(const float* __restrict__ g_in,
                                            const int* __restrict__ csr,
                                            const int* __restrict__ nnz_g,
                                            const float* __restrict__ dinv,
                                            int row0, int bbase, int lane,
                                            float acc[RPW]) {
    int n[RPW], idx[RPW];
    float dv[RPW];
#pragma unroll
    for (int r = 0; r < RPW; ++r) {
        int row = row0 + r;
        n[r] = __builtin_amdgcn_readfirstlane(nnz_g[row]);
        idx[r] = (lane < n[r]) ? csr[row * CAP + lane] : 0;
        dv[r] = (lane < n[r]) ? dinv[bbase + idx[r]] : 0.f;
    }
    spmm8(g_in, bbase, n, idx, dv, lane, acc);
}

// ---------------- K2/K3: g_out = relu(D A D g_in + bias) @ W ----------------
// Epilogue with ZERO readlanes: h -> wave-private LDS, read back as uniform-
// address ds_read_b128 (broadcast, conflict-free); W vector from LDS (1
// ds_read_b32 per d, amortized over 8 rows). 512 v_fmac per wave, d-ascending
// chain per row (bit-identical to R9's order).
__global__ __launch_bounds__(256) void k_layer(const float* __restrict__ g_in,
                                               const int* __restrict__ csr,
                                               const int* __restrict__ nnz_g,
                                               const float* __restrict__ dinv,
                                               const float* __restrict__ bias,
                                               const float* __restrict__ W,
                                               float* __restrict__ g_out) {
    __shared__ float sW[HID * HID];            // 16 KB
    __shared__ float sh[4][RPW][HID];          // 8 KB, wave-private slabs
    for (int i = threadIdx.x; i < HID * HID; i += 256) sW[i] = W[i];
    __syncthreads();                           // sW ready (before epilogue)
    int wv = threadIdx.x >> 6, lane = threadIdx.x & 63;
    int row0 = swz32(blockIdx.x, wv);
    int bbase = row0 & ~(NN - 1);
    float bb = bias[lane];
    float acc[RPW];
    gather_rows(g_in, csr, nnz_g, dinv, row0, bbase, lane, acc);
#pragma unroll
    for (int r = 0; r < RPW; ++r)
        sh[wv][r][lane] = fmaxf(dinv[row0 + r] * acc[r] + bb, 0.f);
    // wave-private LDS: no barrier needed, compiler inserts lgkmcnt
    float o[RPW];
#pragma unroll
    for (int r = 0; r < RPW; ++r) o[r] = 0.f;
#pragma unroll
    for (int dq = 0; dq < HID / 4; ++dq) {
        float w0 = sW[(dq * 4 + 0) * HID + lane];
        float w1 = sW[(dq * 4 + 1) * HID + lane];
        float w2 = sW[(dq * 4 + 2) * HID + lane];
        float w3 = sW[(dq * 4 + 3) * HID + lane];
#pragma unroll
        for (int r = 0; r < RPW; ++r) {
            float4 hq = *reinterpret_cast<const float4*>(&sh[wv][r][dq * 4]);
            o[r] += hq.x * w0;                 // d ascending: same chain as R9
            o[r] += hq.y * w1;
            o[r] += hq.z * w2;
            o[r] += hq.w * w3;
        }
    }
#pragma unroll
    for (int r = 0; r < RPW; ++r)
        g_out[(size_t)(row0 + r) * HID + lane] = o[r];
}

// ---------------- K4: last gather + pool + (last block) fused head ----------
__global__ __launch_bounds__(256) void k_layer3h(const float* __restrict__ g_in,
                                                 const int* __restrict__ csr,
                                                 const int* __restrict__ nnz_g,
                                                 const float* __restrict__ dinv,
                                                 const float* __restrict__ bias,
                                                 float* __restrict__ pooled,
                                                 int* __restrict__ ticket,
                                                 const float* __restrict__ Wf1,
                                                 const float* __restrict__ bf1,
                                                 const float* __restrict__ Wf2,
                                                 const float* __restrict__ bf2,
                                                 float* __restrict__ out) {
    __shared__ float sred[4][HID];
    __shared__ int s_last;
    __shared__ float sp[BATCH * HID];          // 8 KB (head phase)
    __shared__ float shid[BATCH * HEADD];      // 16 KB (head phase)
    int wv = threadIdx.x >> 6, lane = threadIdx.x & 63;
    int row0 = swz32(blockIdx.x, wv);
    int bbase = row0 & ~(NN - 1);
    float bb = bias[lane];
    float acc[RPW];
    gather_rows(g_in, csr, nnz_g, dinv, row0, bbase, lane, acc);
    float s = 0.f;
#pragma unroll
    for (int r = 0; r < RPW; ++r)
        s += fmaxf(dinv[row0 + r] * acc[r] + bb, 0.f);
    sred[wv][lane] = s;
    __syncthreads();
    if (wv == 0) {
        float tot = sred[0][lane] + sred[1][lane] + sred[2][lane] + sred[3][lane];
        atomicAdd(&pooled[(bbase >> 10) * HID + lane], tot);
    }
    __syncthreads();
    if (threadIdx.x == 0) {
        __threadfence();
        int old = atomicAdd(ticket, 1);
        s_last = (old == LAYER_BLOCKS - 1) ? 1 : 0;
    }
    __syncthreads();
    if (s_last) {                              // block-uniform branch
        __threadfence();
        int t = threadIdx.x;
        // coherent read of pooled via atomic fetch-add 0
        for (int i = t; i < BATCH * HID; i += 256)
            sp[i] = atomicAdd(&pooled[i], 0.0f) * (1.0f / NN);
        __syncthreads();
        // hid[b][c] = relu(bf1[c] + sum_d sp[b][d] * Wf1[d][c])
        for (int task = t; task < BATCH * HEADD; task += 256) {
            int b = task >> 7, c = task & (HEADD - 1);
            float a = bf1[c];
            for (int d = 0; d < HID; ++d)
                a += sp[b * HID + d] * Wf1[d * HEADD + c];
            shid[task] = fmaxf(a, 0.f);
        }
        __syncthreads();
        if (t < BATCH) {
            float v = 0.f;
            for (int c = 0; c < HEADD; ++c)
                v += shid[t * HEADD + c] * Wf2[c];
            out[t] = v + bf2[0];
        }
    }
}

extern "C" void kernel_launch(void* const* d_in, const int* in_sizes, int n_in,
                              void* d_out, int out_size, void* d_ws, size_t ws_size,
                              hipStream_t stream) {
    const float* x   = (const float*)d_in[0];
    const float* adj = (const float*)d_in[1];
    const float* W1  = (const float*)d_in[2];
    const float* b1  = (const float*)d_in[3];
    const float* W2  = (const float*)d_in[4];
    const float* b2  = (const float*)d_in[5];
    const float* W3  = (const float*)d_in[6];
    const float* b3  = (const float*)d_in[7];
    const float* Wf1 = (const float*)d_in[8];
    const float* bf1 = (const float*)d_in[9];
    const float* Wf2 = (const float*)d_in[10];
    const float* bf2 = (const float*)d_in[11];
    float* out = (float*)d_out;

    // ws carve: csr(int) 8MB | nnz | dinv | pooled | ticket | g 8MB | h 8MB
    char* ws = (char*)d_ws;
    size_t off = 0;
    int*   csr    = (int*)(ws + off);   off += (size_t)ROWS * CAP * 4;
    int*   nnz_g  = (int*)(ws + off);   off += (size_t)ROWS * 4;
    float* dinv   = (float*)(ws + off); off += (size_t)ROWS * 4;
    float* pooled = (float*)(ws + off); off += 4096 * 4;
    int*   ticket = (int*)(ws + off);   off += 256;
    float* gA     = (float*)(ws + off); off += (size_t)ROWS * HID * 4;
    float* gB     = (float*)(ws + off);

    k_build  <<<ROWS / 4, 256, 0, stream>>>(adj, x, W1, csr, nnz_g, dinv, gA,
                                            pooled, ticket);
    k_layer  <<<LAYER_BLOCKS, 256, 0, stream>>>(gA, csr, nnz_g, dinv, b1, W2, gB);
    k_layer  <<<LAYER_BLOCKS, 256, 0, stream>>>(gB, csr, nnz_g, dinv, b2, W3, gA);
    k_layer3h<<<LAYER_BLOCKS, 256, 0, stream>>>(gA, csr, nnz_g, dinv, b3, pooled,
                                                ticket, Wf1, bf1, Wf2, bf2, out);
}